// Round 2
// baseline (234.220 us; speedup 1.0000x reference)
//
#include <hip/hip_runtime.h>
#include <stdint.h>

// Problem constants (from reference): N=65536 points, M=1024 gaussians, D=2, C=3, K=10
#define M_GAUSS 1024
#define KTOP 10
#define EPSF 1e-6f
#define BLOCK 256

typedef unsigned long long u64;

// Per-gaussian LDS struct (8 floats, 32B aligned for b128 loads):
// [mux, muy, A, B, C, r, g, b] where q = A*dx^2 + B*dx*dy + C*dy^2 = -0.5 d^T Sigma^-1 d
__global__ __launch_bounds__(BLOCK) void renderer_topk(
    const float* __restrict__ x,     // [N,2]
    const float* __restrict__ mus,   // [1,M,2]
    const float* __restrict__ covs,  // [1,M,2,2]
    const float* __restrict__ cols,  // [1,M,3]
    float* __restrict__ out,         // [N,3]
    int N)
{
    __shared__ float g[M_GAUSS * 8];

    const int t = threadIdx.x;

    // ---- Stage gaussian params into LDS (each block redundantly; trivial cost) ----
    #pragma unroll
    for (int k = 0; k < M_GAUSS / BLOCK; ++k) {
        const int m = t + BLOCK * k;
        const float4 cv = ((const float4*)covs)[m];      // c00 c01 c10 c11
        const float2 mu = ((const float2*)mus)[m];
        const float det = cv.x * cv.w - cv.y * cv.z;
        const float inv = 1.0f / det;
        const float ia = cv.w * inv;    // Sigma^-1[0][0]
        const float ib = -cv.y * inv;   // Sigma^-1[0][1]
        const float ic = cv.x * inv;    // Sigma^-1[1][1]
        g[m * 8 + 0] = mu.x;
        g[m * 8 + 1] = mu.y;
        g[m * 8 + 2] = -0.5f * ia;      // A
        g[m * 8 + 3] = -ib;             // B (covers the 2*ib cross term)
        g[m * 8 + 4] = -0.5f * ic;      // C
        g[m * 8 + 5] = cols[m * 3 + 0];
        g[m * 8 + 6] = cols[m * 3 + 1];
        g[m * 8 + 7] = cols[m * 3 + 2];
    }
    __syncthreads();

    const int n = blockIdx.x * BLOCK + t;
    if (n >= N) return;

    const float2 xv = ((const float2*)x)[n];
    const float x0 = xv.x, x1 = xv.y;

    // Top-K as 64-bit packed keys: EXACT order-preserving float->uint xform of q in
    // bits [41:10], (1023-m) in low 10. Larger key == larger q; exact q ties prefer
    // lower m, matching jax top_k. Selection is bit-exact vs the reference.
    u64 topk[KTOP];
    #pragma unroll
    for (int j = 0; j < KTOP; ++j) topk[j] = 0ull;

    #pragma unroll 4
    for (int m = 0; m < M_GAUSS; ++m) {
        const float4 p = *(const float4*)&g[m * 8];      // mux muy A B
        const float Cc = g[m * 8 + 4];
        const float dx = x0 - p.x;
        const float dy = x1 - p.y;
        const float q = fmaf(fmaf(p.z, dx, p.w * dy), dx, Cc * (dy * dy));
        const uint32_t b = __float_as_uint(q);
        const uint32_t msk = (uint32_t)((int32_t)b >> 31) | 0x80000000u;
        const uint32_t kb = b ^ msk;                     // order-preserving, exact
        const u64 key = ((u64)kb << 10) | (u64)(M_GAUSS - 1 - m);
        if (key > topk[KTOP - 1]) {
            // Parallel insert: 10 independent compares, then 2 select levels.
            bool c[KTOP];
            #pragma unroll
            for (int j = 0; j < KTOP; ++j) c[j] = topk[j] >= key;
            #pragma unroll
            for (int j = KTOP - 1; j >= 1; --j)
                topk[j] = c[j] ? topk[j] : (c[j - 1] ? key : topk[j - 1]);
            topk[0] = c[0] ? topk[0] : key;
        }
    }

    // ---- Decode winners: exact q recovered from the key (inverse xform), colors from LDS ----
    float vsum = 0.0f, r = 0.0f, gg = 0.0f, bb = 0.0f;
    #pragma unroll
    for (int j = 0; j < KTOP; ++j) {
        const u64 key = topk[j];
        const int m = (M_GAUSS - 1) - (int)(key & 1023u);
        const uint32_t kb = (uint32_t)(key >> 10);
        // inverse of (b ^ ((b>>31)|0x80000000)): top bit set -> was positive
        const uint32_t b = ((int32_t)kb < 0) ? (kb ^ 0x80000000u) : ~kb;
        const float q = __uint_as_float(b);
        const float v = __expf(q);
        vsum += v;
        r  = fmaf(v, g[m * 8 + 5], r);
        gg = fmaf(v, g[m * 8 + 6], gg);
        bb = fmaf(v, g[m * 8 + 7], bb);
    }
    const float s = 1.0f / (vsum + EPSF);
    out[n * 3 + 0] = r * s;
    out[n * 3 + 1] = gg * s;
    out[n * 3 + 2] = bb * s;
}

extern "C" void kernel_launch(void* const* d_in, const int* in_sizes, int n_in,
                              void* d_out, int out_size, void* d_ws, size_t ws_size,
                              hipStream_t stream) {
    const float* x    = (const float*)d_in[0];
    const float* mus  = (const float*)d_in[1];
    const float* covs = (const float*)d_in[2];
    const float* cols = (const float*)d_in[3];
    float* out = (float*)d_out;
    const int N = in_sizes[0] / 2;
    const int grid = (N + BLOCK - 1) / BLOCK;
    renderer_topk<<<grid, BLOCK, 0, stream>>>(x, mus, covs, cols, out, N);
}

// Round 3
// 167.845 us; speedup vs baseline: 1.3955x; 1.3955x over previous
//
#include <hip/hip_runtime.h>
#include <stdint.h>

// N=65536 points, M=1024 gaussians, D=2, C=3, K=10
#define M_GAUSS 1024
#define KTOP 10
#define EPSF 1e-6f
#define BLOCK 256
#define PTS_PER_BLOCK 64
#define NSLICE 4
#define SLICE_M (M_GAUSS / NSLICE)   // 256

typedef unsigned long long u64;

// Layout: wave s of each block handles slice s (gaussians [s*256, s*256+256)) for
// the block's 64 points; lane = point. All lanes in a wave read the same gaussian
// -> LDS broadcast, no conflicts. 4 waves/SIMD hides VALU/LDS latency (round-2
// counters: 1 wave/SIMD, VALUBusy 41%, 59% stall).
__global__ __launch_bounds__(BLOCK, 4) void renderer_topk(
    const float* __restrict__ x,     // [N,2]
    const float* __restrict__ mus,   // [1,M,2]
    const float* __restrict__ covs,  // [1,M,2,2]
    const float* __restrict__ cols,  // [1,M,3]
    float* __restrict__ out,         // [N,3]
    int N)
{
    // garr1[m] = (mux, muy, A, B); garr2[m] = (C, r, g, b)
    // q = A*dx^2 + B*dx*dy + C*dy^2 = -0.5 d^T Sigma^-1 d
    __shared__ float4 smem[2 * M_GAUSS];          // 32 KB
    float4* garr1 = smem;
    float4* garr2 = smem + M_GAUSS;
    u64* mbuf = (u64*)smem;   // merge buffer overlays garr1 after main loop (15 KB <= 16 KB)

    const int t = threadIdx.x;

    // ---- Stage gaussian params (each block redundantly; inputs are L2/L3-resident) ----
    #pragma unroll
    for (int k = 0; k < M_GAUSS / BLOCK; ++k) {
        const int m = t + BLOCK * k;
        const float4 cv = ((const float4*)covs)[m];      // c00 c01 c10 c11
        const float2 mu = ((const float2*)mus)[m];
        const float det = cv.x * cv.w - cv.y * cv.z;
        const float inv = 1.0f / det;
        garr1[m] = make_float4(mu.x, mu.y, -0.5f * cv.w * inv, cv.y * inv);
        garr2[m] = make_float4(-0.5f * cv.x * inv,
                               cols[m * 3 + 0], cols[m * 3 + 1], cols[m * 3 + 2]);
    }
    __syncthreads();

    const int lane = t & 63;              // point within block
    const int s = t >> 6;                 // slice index == wave index
    int p = blockIdx.x * PTS_PER_BLOCK + lane;
    const bool valid = (p < N);
    if (!valid) p = N - 1;                // clamp; all threads still reach barriers

    const float2 xv = ((const float2*)x)[p];
    const float x0 = xv.x, x1 = xv.y;

    // Top-K as 64-bit keys: exact order-preserving xform of q in bits [41:10],
    // (1023-m) in low 10 -> exact value compare, lowest-index tie-break (jax-stable).
    u64 topk[KTOP];
    #pragma unroll
    for (int j = 0; j < KTOP; ++j) topk[j] = 0ull;

    const int mbase = s * SLICE_M;
    #pragma unroll 4
    for (int i = 0; i < SLICE_M; ++i) {
        const int m = mbase + i;
        const float4 p1 = garr1[m];
        const float Cc = garr2[m].x;
        const float dx = x0 - p1.x;
        const float dy = x1 - p1.y;
        const float q = fmaf(fmaf(p1.z, dx, p1.w * dy), dx, Cc * (dy * dy));
        const uint32_t b = __float_as_uint(q);
        const uint32_t msk = (uint32_t)((int32_t)b >> 31) | 0x80000000u;
        const uint32_t kb = b ^ msk;
        const u64 key = ((u64)kb << 10) | (u64)(M_GAUSS - 1 - m);
        // Branchless sorted insert (wave-any-insert prob ~1 anyway; branchless
        // removes exec-mask churn and lets ds_reads pipeline across iterations).
        bool c[KTOP];
        #pragma unroll
        for (int j = 0; j < KTOP; ++j) c[j] = topk[j] >= key;
        #pragma unroll
        for (int j = KTOP - 1; j >= 1; --j)
            topk[j] = c[j] ? topk[j] : (c[j - 1] ? key : topk[j - 1]);
        topk[0] = c[0] ? topk[0] : key;
    }

    __syncthreads();                      // everyone done reading garr1

    // Slices 1..3 publish their lists; layout [row][point] -> b64 lane-stride 8B.
    if (s != 0) {
        #pragma unroll
        for (int j = 0; j < KTOP; ++j)
            mbuf[((s - 1) * KTOP + j) * PTS_PER_BLOCK + lane] = topk[j];
    }
    __syncthreads();

    if (s == 0) {
        // Merge the other 3 slices' 30 keys into our sorted list.
        #pragma unroll 2
        for (int r = 0; r < (NSLICE - 1) * KTOP; ++r) {
            const u64 key = mbuf[r * PTS_PER_BLOCK + lane];
            bool c[KTOP];
            #pragma unroll
            for (int j = 0; j < KTOP; ++j) c[j] = topk[j] >= key;
            #pragma unroll
            for (int j = KTOP - 1; j >= 1; --j)
                topk[j] = c[j] ? topk[j] : (c[j - 1] ? key : topk[j - 1]);
            topk[0] = c[0] ? topk[0] : key;
        }

        // Decode winners: exact q recovered from key (inverse xform), colors from LDS.
        float vsum = 0.0f, rc = 0.0f, gc = 0.0f, bc = 0.0f;
        #pragma unroll
        for (int j = 0; j < KTOP; ++j) {
            const u64 key = topk[j];
            const int m = (M_GAUSS - 1) - (int)(key & 1023u);
            const uint32_t kb = (uint32_t)(key >> 10);
            const uint32_t b = ((int32_t)kb < 0) ? (kb ^ 0x80000000u) : ~kb;
            const float q = __uint_as_float(b);
            const float v = __expf(q);
            const float4 p2 = garr2[m];
            vsum += v;
            rc = fmaf(v, p2.y, rc);
            gc = fmaf(v, p2.z, gc);
            bc = fmaf(v, p2.w, bc);
        }
        const float sc = 1.0f / (vsum + EPSF);
        if (valid) {
            out[p * 3 + 0] = rc * sc;
            out[p * 3 + 1] = gc * sc;
            out[p * 3 + 2] = bc * sc;
        }
    }
}

extern "C" void kernel_launch(void* const* d_in, const int* in_sizes, int n_in,
                              void* d_out, int out_size, void* d_ws, size_t ws_size,
                              hipStream_t stream) {
    const float* x    = (const float*)d_in[0];
    const float* mus  = (const float*)d_in[1];
    const float* covs = (const float*)d_in[2];
    const float* cols = (const float*)d_in[3];
    float* out = (float*)d_out;
    const int N = in_sizes[0] / 2;
    const int grid = (N + PTS_PER_BLOCK - 1) / PTS_PER_BLOCK;
    renderer_topk<<<grid, BLOCK, 0, stream>>>(x, mus, covs, cols, out, N);
}

// Round 4
// 135.600 us; speedup vs baseline: 1.7273x; 1.2378x over previous
//
#include <hip/hip_runtime.h>
#include <stdint.h>

// N=65536 points, M=1024 gaussians, D=2, C=3, K=10
#define MG 1024
#define KTOP 10
#define EPSF 1e-6f
#define GRID_C 32
#define NBINS (GRID_C * GRID_C)

typedef unsigned long long u64;

__device__ __forceinline__ int cell_of(float x0, float x1) {
    int ix = (int)(x0 * GRID_C); ix = ix < 0 ? 0 : (ix > GRID_C - 1 ? GRID_C - 1 : ix);
    int iy = (int)(x1 * GRID_C); iy = iy < 0 ? 0 : (iy > GRID_C - 1 ? GRID_C - 1 : iy);
    return iy * GRID_C + ix;
}

__global__ __launch_bounds__(256) void k_zero(uint32_t* __restrict__ hist) {
    hist[blockIdx.x * 256 + threadIdx.x] = 0u;
}

__global__ __launch_bounds__(256) void k_hist(const float* __restrict__ x,
                                              uint32_t* __restrict__ hist, int N) {
    const int n = blockIdx.x * 256 + threadIdx.x;
    if (n < N) atomicAdd(&hist[cell_of(x[2 * n], x[2 * n + 1])], 1u);
}

__global__ __launch_bounds__(NBINS) void k_scan(const uint32_t* __restrict__ hist,
                                                uint32_t* __restrict__ cursor) {
    __shared__ uint32_t s[NBINS];
    const int t = threadIdx.x;
    const uint32_t v = hist[t];
    s[t] = v;
    __syncthreads();
    for (int o = 1; o < NBINS; o <<= 1) {
        const uint32_t add = (t >= o) ? s[t - o] : 0u;
        __syncthreads();
        s[t] += add;
        __syncthreads();
    }
    cursor[t] = s[t] - v;   // exclusive prefix
}

__global__ __launch_bounds__(256) void k_scatter(const float* __restrict__ x,
                                                 uint32_t* __restrict__ cursor,
                                                 uint32_t* __restrict__ perm, int N) {
    const int n = blockIdx.x * 256 + threadIdx.x;
    if (n < N) {
        const uint32_t r = atomicAdd(&cursor[cell_of(x[2 * n], x[2 * n + 1])], 1u);
        perm[r] = (uint32_t)n;
    }
}

// Main: block = 256 = 2 point-groups x 2 slices. Wave's 64 lanes = 64 spatially
// coherent points (via perm) -> screened insert's wave-any prob collapses after
// warmup. Selection stays bit-exact: u64 key network, float screen uses >= so
// exact-value ties (index tie-break) still enter the network.
__global__ __launch_bounds__(256, 2) void k_main(
    const float* __restrict__ x, const float* __restrict__ mus,
    const float* __restrict__ covs, const float* __restrict__ cols,
    const uint32_t* __restrict__ perm, float* __restrict__ out, int N)
{
    __shared__ float4 garr[MG];            // mux, muy, A, B
    __shared__ float  garrC[MG];           // C       (q = A dx^2 + B dx dy + C dy^2)
    __shared__ float4 gcol[MG];            // r, g, b, -
    __shared__ u64    mbuf[2][KTOP][64];   // slice-1 publish buffer

    const int t = threadIdx.x;
    #pragma unroll
    for (int k = 0; k < MG / 256; ++k) {
        const int m = t + 256 * k;
        const float4 cv = ((const float4*)covs)[m];
        const float2 mu = ((const float2*)mus)[m];
        const float inv = 1.0f / (cv.x * cv.w - cv.y * cv.z);
        garr[m]  = make_float4(mu.x, mu.y, -0.5f * cv.w * inv, cv.y * inv);
        garrC[m] = -0.5f * cv.x * inv;
        gcol[m]  = make_float4(cols[m * 3], cols[m * 3 + 1], cols[m * 3 + 2], 0.0f);
    }
    __syncthreads();

    const int lane = t & 63, w = t >> 6, pg = w >> 1, sl = w & 1;
    int idx = blockIdx.x * 128 + pg * 64 + lane;
    const bool valid = (idx < N);
    if (!valid) idx = N - 1;
    const int p = perm ? (int)perm[idx] : idx;
    const float2 xv = ((const float2*)x)[p];
    const float x0 = xv.x, x1 = xv.y;

    u64 topk[KTOP];
    const u64 SENT = ((u64)0x007FFFFFull) << 10;   // packed -inf, index 1023
    #pragma unroll
    for (int j = 0; j < KTOP; ++j) topk[j] = SENT;
    float thr = __uint_as_float(0xff800000u);      // -inf: warmup always passes screen

    auto net_insert = [&](u64 key) {
        bool c[KTOP];
        #pragma unroll
        for (int j = 0; j < KTOP; ++j) c[j] = topk[j] >= key;
        #pragma unroll
        for (int j = KTOP - 1; j >= 1; --j)
            topk[j] = c[j] ? topk[j] : (c[j - 1] ? key : topk[j - 1]);
        topk[0] = c[0] ? topk[0] : key;
    };
    auto ins = [&](float q, int m) {
        if (__any(q >= thr)) {
            const uint32_t b = __float_as_uint(q);
            const uint32_t msk = (uint32_t)((int32_t)b >> 31) | 0x80000000u;
            net_insert(((u64)(b ^ msk) << 10) | (u64)(MG - 1 - m));
            const uint32_t kb = (uint32_t)(topk[KTOP - 1] >> 10);
            const uint32_t bb = ((int32_t)kb < 0) ? (kb ^ 0x80000000u) : ~kb;
            thr = __uint_as_float(bb);             // value of current 10th
        }
    };

    const int mbase = sl * (MG / 2);
    for (int i = 0; i < MG / 2; i += 4) {
        const int m = mbase + i;
        const float4 p0 = garr[m], p1 = garr[m + 1], p2 = garr[m + 2], p3 = garr[m + 3];
        const float4 c4 = *(const float4*)&garrC[m];
        const float dx0 = x0 - p0.x, dy0 = x1 - p0.y;
        const float dx1 = x0 - p1.x, dy1 = x1 - p1.y;
        const float dx2 = x0 - p2.x, dy2 = x1 - p2.y;
        const float dx3 = x0 - p3.x, dy3 = x1 - p3.y;
        const float q0 = fmaf(fmaf(p0.z, dx0, p0.w * dy0), dx0, c4.x * (dy0 * dy0));
        const float q1 = fmaf(fmaf(p1.z, dx1, p1.w * dy1), dx1, c4.y * (dy1 * dy1));
        const float q2 = fmaf(fmaf(p2.z, dx2, p2.w * dy2), dx2, c4.z * (dy2 * dy2));
        const float q3 = fmaf(fmaf(p3.z, dx3, p3.w * dy3), dx3, c4.w * (dy3 * dy3));
        const float qm = fmaxf(fmaxf(q0, q1), fmaxf(q2, q3));
        if (__any(qm >= thr)) {
            ins(q0, m); ins(q1, m + 1); ins(q2, m + 2); ins(q3, m + 3);
        }
    }

    if (sl == 1) {
        #pragma unroll
        for (int j = 0; j < KTOP; ++j) mbuf[pg][j][lane] = topk[j];
    }
    __syncthreads();

    if (sl == 0) {
        #pragma unroll 1
        for (int r = 0; r < KTOP; ++r) {
            const u64 key = mbuf[pg][r][lane];
            if (__any(key > topk[KTOP - 1])) net_insert(key);
        }
        float vsum = 0.0f, rc = 0.0f, gc = 0.0f, bc = 0.0f;
        #pragma unroll
        for (int j = 0; j < KTOP; ++j) {
            const u64 key = topk[j];
            const int m = (MG - 1) - (int)(key & 1023u);
            const uint32_t kb = (uint32_t)(key >> 10);
            const uint32_t b = ((int32_t)kb < 0) ? (kb ^ 0x80000000u) : ~kb;
            const float v = __expf(__uint_as_float(b));
            const float4 cl = gcol[m];
            vsum += v;
            rc = fmaf(v, cl.x, rc);
            gc = fmaf(v, cl.y, gc);
            bc = fmaf(v, cl.z, bc);
        }
        const float s = 1.0f / (vsum + EPSF);
        if (valid) {
            out[p * 3 + 0] = rc * s;
            out[p * 3 + 1] = gc * s;
            out[p * 3 + 2] = bc * s;
        }
    }
}

extern "C" void kernel_launch(void* const* d_in, const int* in_sizes, int n_in,
                              void* d_out, int out_size, void* d_ws, size_t ws_size,
                              hipStream_t stream) {
    const float* x    = (const float*)d_in[0];
    const float* mus  = (const float*)d_in[1];
    const float* covs = (const float*)d_in[2];
    const float* cols = (const float*)d_in[3];
    float* out = (float*)d_out;
    const int N = in_sizes[0] / 2;

    uint32_t* hist   = (uint32_t*)d_ws;
    uint32_t* cursor = hist + NBINS;
    uint32_t* perm   = cursor + NBINS;
    const size_t need = (size_t)(2 * NBINS + N) * sizeof(uint32_t);
    const bool use_sort = (ws_size >= need);

    if (use_sort) {
        k_zero<<<NBINS / 256, 256, 0, stream>>>(hist);
        k_hist<<<(N + 255) / 256, 256, 0, stream>>>(x, hist, N);
        k_scan<<<1, NBINS, 0, stream>>>(hist, cursor);
        k_scatter<<<(N + 255) / 256, 256, 0, stream>>>(x, cursor, perm, N);
    }
    k_main<<<(N + 127) / 128, 256, 0, stream>>>(x, mus, covs, cols,
                                                use_sort ? perm : (const uint32_t*)nullptr,
                                                out, N);
}